// Round 1
// baseline (680.524 us; speedup 1.0000x reference)
//
#include <hip/hip_runtime.h>

#define HH 256
#define WW 256
#define NB 4
#define NC 4
#define NPIX (HH*WW)            // 65536
#define NIMG (NB*NC)            // 16
#define NPROB (NIMG*4)          // 64 DT problems
#define TOTAL (NB*NC*HH*WW)     // 1048576

__device__ __forceinline__ float wave_reduce(float v) {
    #pragma unroll
    for (int off = 32; off > 0; off >>= 1) v += __shfl_down(v, off);
    return v;
}

// probs = softmax(pred, axis=1)
__global__ void softmax_kernel(const float* __restrict__ pred, float* __restrict__ probs) {
    int idx = blockIdx.x * 256 + threadIdx.x;   // over NB*HH*WW
    if (idx >= NB * NPIX) return;
    int b = idx >> 16;
    int pix = idx & (NPIX - 1);
    const float* base = pred + (size_t)b * NC * NPIX + pix;
    float v0 = base[0 * NPIX], v1 = base[1 * NPIX], v2 = base[2 * NPIX], v3 = base[3 * NPIX];
    float m = fmaxf(fmaxf(v0, v1), fmaxf(v2, v3));
    float e0 = expf(v0 - m), e1 = expf(v1 - m), e2 = expf(v2 - m), e3 = expf(v3 - m);
    float inv = 1.0f / (e0 + e1 + e2 + e3);
    float* ob = probs + (size_t)b * NC * NPIX + pix;
    ob[0 * NPIX] = e0 * inv;
    ob[1 * NPIX] = e1 * inv;
    ob[2 * NPIX] = e2 * inv;
    ob[3 * NPIX] = e3 * inv;
}

// flags[u]: u = img*2 + src (src 0 = pred-fg, 1 = target-fg); any(fg) per image
__global__ void flags_kernel(const float* __restrict__ probs, const int* __restrict__ target,
                             int* __restrict__ flags) {
    int u = blockIdx.x;           // 0..31
    int img = u >> 1, src = u & 1;
    int b = img >> 2, c = img & 3;
    bool any = false;
    for (int t = threadIdx.x; t < NPIX; t += 256) {
        bool fg;
        if (src == 0) fg = probs[(size_t)img * NPIX + t] > 0.5f;
        else          fg = (target[(size_t)b * NPIX + t] == c);
        any |= fg;
    }
    unsigned long long ball = __ballot(any);
    __shared__ int s_any[4];
    int wave = threadIdx.x >> 6;
    if ((threadIdx.x & 63) == 0) s_any[wave] = (ball != 0ULL);
    __syncthreads();
    if (threadIdx.x == 0)
        flags[u] = s_any[0] | s_any[1] | s_any[2] | s_any[3];
}

// Pass 1: per-row 1D squared DT. block = (k, y), thread = x.
// k = img*4 + v; v: 0=~fgP, 1=fgP, 2=~fgT, 3=fgT
__global__ void dt_pass1(const float* __restrict__ probs, const int* __restrict__ target,
                         float* __restrict__ g) {
    int blk = blockIdx.x;
    int y = blk & 255;
    int k = blk >> 8;
    int v = k & 3;
    int img = k >> 2;
    int b = img >> 2, c = img & 3;
    int x = threadIdx.x;
    __shared__ float f[WW];
    bool site;
    if (v < 2) {
        bool fg = probs[((size_t)img * HH + y) * WW + x] > 0.5f;
        site = (v == 0) ? !fg : fg;
    } else {
        bool fg = (target[((size_t)b * HH + y) * WW + x] == c);
        site = (v == 2) ? !fg : fg;
    }
    f[x] = site ? 0.0f : 1000000000.0f;
    __syncthreads();
    float mn = f[0] + (float)(x * x);
    #pragma unroll 8
    for (int j = 1; j < WW; ++j) {
        float d = (float)(x - j);
        mn = fminf(mn, fmaf(d, d, f[j]));
    }
    g[((size_t)k * HH + y) * WW + x] = mn;
}

// Pass 2: per-column 1D squared DT on g, then sqrt. block = (k, x), thread = row.
__global__ void dt_pass2(const float* __restrict__ g, float* __restrict__ dt) {
    int blk = blockIdx.x;
    int x = blk & 255;
    int k = blk >> 8;
    int i = threadIdx.x;
    __shared__ float f[HH];
    f[i] = g[((size_t)k * HH + i) * WW + x];
    __syncthreads();
    float mn = f[0] + (float)(i * i);
    #pragma unroll 8
    for (int j = 1; j < HH; ++j) {
        float d = (float)(i - j);
        mn = fminf(mn, fmaf(d, d, f[j]));
    }
    dt[((size_t)k * HH + i) * WW + x] = sqrtf(mn);
}

// Loss: per-element (p-t)^2 * (pred_dt^2 + target_dt^2), block partial sums.
__global__ void loss_kernel(const float* __restrict__ probs, const int* __restrict__ target,
                            const float* __restrict__ dt, const int* __restrict__ flags,
                            float* __restrict__ partials) {
    int idx = blockIdx.x * 256 + threadIdx.x;   // over TOTAL, x fastest
    int img = idx >> 16;                        // b*4 + c
    int b = img >> 2, c = img & 3;
    int pix = idx & (NPIX - 1);

    float p = probs[idx];
    float t = (target[(size_t)b * NPIX + pix] == c) ? 1.0f : 0.0f;
    float pe = (p - t) * (p - t);

    size_t kbase = ((size_t)img * 4) * NPIX + pix;
    float pd = 0.0f, td = 0.0f;
    if (flags[img * 2 + 0]) pd = dt[kbase] + dt[kbase + (size_t)NPIX];
    if (flags[img * 2 + 1]) td = dt[kbase + 2 * (size_t)NPIX] + dt[kbase + 3 * (size_t)NPIX];
    float distance = pd * pd + td * td;
    float val = pe * distance;

    val = wave_reduce(val);
    __shared__ float s[4];
    int lane = threadIdx.x & 63, wave = threadIdx.x >> 6;
    if (lane == 0) s[wave] = val;
    __syncthreads();
    if (threadIdx.x == 0)
        partials[blockIdx.x] = s[0] + s[1] + s[2] + s[3];
}

__global__ void final_kernel(const float* __restrict__ partials, float* __restrict__ out) {
    float a = 0.0f;
    for (int i = threadIdx.x; i < 4096; i += 256) a += partials[i];
    a = wave_reduce(a);
    __shared__ float s[4];
    int lane = threadIdx.x & 63, wave = threadIdx.x >> 6;
    if (lane == 0) s[wave] = a;
    __syncthreads();
    if (threadIdx.x == 0)
        out[0] = (s[0] + s[1] + s[2] + s[3]) * (1.0f / (float)TOTAL);
}

extern "C" void kernel_launch(void* const* d_in, const int* in_sizes, int n_in,
                              void* d_out, int out_size, void* d_ws, size_t ws_size,
                              hipStream_t stream) {
    const float* pred  = (const float*)d_in[0];
    const int* target  = (const int*)d_in[1];
    float* out = (float*)d_out;

    float* ws = (float*)d_ws;
    float* probs    = ws;                         // 1,048,576 floats
    float* g        = ws + 1048576;               // 4,194,304 floats
    float* dt       = ws + 5242880;               // 4,194,304 floats
    float* partials = ws + 9437184;               // 4096 floats
    int*   flags    = (int*)(ws + 9441280);       // 32 ints

    softmax_kernel<<<(NB * NPIX) / 256, 256, 0, stream>>>(pred, probs);
    flags_kernel<<<32, 256, 0, stream>>>(probs, target, flags);
    dt_pass1<<<NPROB * HH, 256, 0, stream>>>(probs, target, g);
    dt_pass2<<<NPROB * WW, 256, 0, stream>>>(g, dt);
    loss_kernel<<<TOTAL / 256, 256, 0, stream>>>(probs, target, dt, flags, partials);
    final_kernel<<<1, 256, 0, stream>>>(partials, out);
}

// Round 2
// 148.508 us; speedup vs baseline: 4.5824x; 4.5824x over previous
//
#include <hip/hip_runtime.h>

#define HH 256
#define WW 256
#define NB 4
#define NC 4
#define NPIX (HH*WW)            // 65536
#define NIMG (NB*NC)            // 16
#define TOTAL (NB*NC*HH*WW)     // 1048576
#define INF_G (1<<30)

__device__ __forceinline__ float wave_reduce(float v) {
    #pragma unroll
    for (int off = 32; off > 0; off >>= 1) v += __shfl_down(v, off);
    return v;
}

// probs = softmax(pred, axis=1)
__global__ void softmax_kernel(const float* __restrict__ pred, float* __restrict__ probs) {
    int idx = blockIdx.x * 256 + threadIdx.x;   // over NB*HH*WW
    int b = idx >> 16;
    int pix = idx & (NPIX - 1);
    const float* base = pred + (size_t)b * NC * NPIX + pix;
    float v0 = base[0 * NPIX], v1 = base[1 * NPIX], v2 = base[2 * NPIX], v3 = base[3 * NPIX];
    float m = fmaxf(fmaxf(v0, v1), fmaxf(v2, v3));
    float e0 = expf(v0 - m), e1 = expf(v1 - m), e2 = expf(v2 - m), e3 = expf(v3 - m);
    float inv = 1.0f / (e0 + e1 + e2 + e3);
    float* ob = probs + (size_t)b * NC * NPIX + pix;
    ob[0 * NPIX] = e0 * inv;
    ob[1 * NPIX] = e1 * inv;
    ob[2 * NPIX] = e2 * inv;
    ob[3 * NPIX] = e3 * inv;
}

__global__ void init_kernel(int* __restrict__ has) {
    has[threadIdx.x] = 0;       // 64 entries
}

// distance from x to nearest set bit in a 256-bit mask (4 u64 words); INT_MAX if none
__device__ __forceinline__ int nearest_dist(const unsigned long long* m, int x) {
    int best = 0x7fffffff;
    #pragma unroll
    for (int w = 0; w < 4; ++w) {
        unsigned long long mm = m[w];
        if (!mm) continue;
        int rel = x - (w << 6);
        // left side: highest set bit at position <= rel
        unsigned long long lmask = (rel >= 63) ? ~0ull
                                 : ((rel < 0) ? 0ull : ((2ull << (rel & 63)) - 1ull));
        unsigned long long lm = mm & lmask;
        if (lm) best = min(best, rel - (63 - __clzll(lm)));
        // right side: lowest set bit at position >= rel
        unsigned long long rmask = (rel <= 0) ? ~0ull
                                 : ((rel > 63) ? 0ull : (~0ull << (rel & 63)));
        unsigned long long rm = mm & rmask;
        if (rm) best = min(best, (__ffsll((long long)rm) - 1) - rel);
    }
    return best;
}

// Row pass: per (img, y): build 256-bit site masks for 4 variants, nearest-bit distance.
// dbuf layout: ushort4 per (img,y,x): {d_v0, d_v1, d_v2, d_v3}; 0xFFFF = row empty.
// v0 = ~fgP, v1 = fgP, v2 = ~fgT, v3 = fgT
__global__ void dt_rows(const float* __restrict__ probs, const int* __restrict__ target,
                        ushort4* __restrict__ dbuf, int* __restrict__ has) {
    int blk = blockIdx.x;
    int img = blk >> 8, y = blk & 255;
    int b = img >> 2, c = img & 3;
    int x = threadIdx.x;

    float p = probs[((size_t)img * HH + y) * WW + x];
    int tc  = target[((size_t)b * HH + y) * WW + x];
    bool fgP = p > 0.5f;
    bool fgT = (tc == c);

    __shared__ unsigned long long mP[4], mT[4];
    unsigned long long bp = __ballot(fgP);
    unsigned long long bt = __ballot(fgT);
    int wave = x >> 6;
    if ((x & 63) == 0) { mP[wave] = bp; mT[wave] = bt; }
    __syncthreads();

    unsigned long long wp[4], wt[4], np[4], nt[4];
    #pragma unroll
    for (int w = 0; w < 4; ++w) {
        wp[w] = mP[w]; wt[w] = mT[w];
        np[w] = ~wp[w]; nt[w] = ~wt[w];
    }

    int d0 = nearest_dist(np, x);   // ~fgP
    int d1 = nearest_dist(wp, x);   // fgP
    int d2 = nearest_dist(nt, x);   // ~fgT
    int d3 = nearest_dist(wt, x);   // fgT

    ushort4 out;
    out.x = (d0 > 255) ? 0xFFFF : (unsigned short)d0;
    out.y = (d1 > 255) ? 0xFFFF : (unsigned short)d1;
    out.z = (d2 > 255) ? 0xFFFF : (unsigned short)d2;
    out.w = (d3 > 255) ? 0xFFFF : (unsigned short)d3;
    dbuf[((size_t)img * HH + y) * WW + x] = out;

    if (x == 0) {
        if ((np[0] | np[1] | np[2] | np[3]) != 0ull) atomicOr(&has[img * 4 + 0], 1);
        if ((wp[0] | wp[1] | wp[2] | wp[3]) != 0ull) atomicOr(&has[img * 4 + 1], 1);
        if ((nt[0] | nt[1] | nt[2] | nt[3]) != 0ull) atomicOr(&has[img * 4 + 2], 1);
        if ((wt[0] | wt[1] | wt[2] | wt[3]) != 0ull) atomicOr(&has[img * 4 + 3], 1);
    }
}

// Column pass + loss, fused. block = (img, x), thread = y.
// best(y) = min_j d_row(j)^2 + (y-j)^2, searched outward with early exit.
__global__ void dt_cols_loss(const ushort4* __restrict__ dbuf, const float* __restrict__ probs,
                             const int* __restrict__ target, const int* __restrict__ has,
                             float* __restrict__ partials) {
    int blk = blockIdx.x;
    int img = blk >> 8, x = blk & 255;
    int b = img >> 2, c = img & 3;
    int y = threadIdx.x;

    __shared__ int g[4][HH];
    ushort4 dv = dbuf[((size_t)img * HH + y) * WW + x];
    g[0][y] = (dv.x == 0xFFFF) ? INF_G : (int)dv.x * (int)dv.x;
    g[1][y] = (dv.y == 0xFFFF) ? INF_G : (int)dv.y * (int)dv.y;
    g[2][y] = (dv.z == 0xFFFF) ? INF_G : (int)dv.z * (int)dv.z;
    g[3][y] = (dv.w == 0xFFFF) ? INF_G : (int)dv.w * (int)dv.w;
    __syncthreads();

    float dt[4];
    #pragma unroll
    for (int v = 0; v < 4; ++v) {
        int best = g[v][y];
        for (int s = 1; s < HH; ++s) {
            int ss = s * s;
            if (ss >= best) break;
            int jm = y - s;
            if (jm >= 0) best = min(best, g[v][jm] + ss);
            int jp = y + s;
            if (jp < HH) best = min(best, g[v][jp] + ss);
        }
        dt[v] = (best >= INF_G) ? sqrtf(1.0e9f) : sqrtf((float)best);
    }

    int hs1 = has[img * 4 + 1];     // any(fgP)
    int hs3 = has[img * 4 + 3];     // any(fgT)

    float p = probs[((size_t)img * HH + y) * WW + x];
    float t = (target[((size_t)b * HH + y) * WW + x] == c) ? 1.0f : 0.0f;
    float pe = (p - t) * (p - t);
    float pd = hs1 ? (dt[0] + dt[1]) : 0.0f;
    float td = hs3 ? (dt[2] + dt[3]) : 0.0f;
    float val = pe * (pd * pd + td * td);

    val = wave_reduce(val);
    __shared__ float sred[4];
    int lane = threadIdx.x & 63, wv = threadIdx.x >> 6;
    if (lane == 0) sred[wv] = val;
    __syncthreads();
    if (threadIdx.x == 0)
        partials[blk] = sred[0] + sred[1] + sred[2] + sred[3];
}

__global__ void final_kernel(const float* __restrict__ partials, float* __restrict__ out) {
    float a = 0.0f;
    for (int i = threadIdx.x; i < 4096; i += 256) a += partials[i];
    a = wave_reduce(a);
    __shared__ float s[4];
    int lane = threadIdx.x & 63, wave = threadIdx.x >> 6;
    if (lane == 0) s[wave] = a;
    __syncthreads();
    if (threadIdx.x == 0)
        out[0] = (s[0] + s[1] + s[2] + s[3]) * (1.0f / (float)TOTAL);
}

extern "C" void kernel_launch(void* const* d_in, const int* in_sizes, int n_in,
                              void* d_out, int out_size, void* d_ws, size_t ws_size,
                              hipStream_t stream) {
    const float* pred  = (const float*)d_in[0];
    const int* target  = (const int*)d_in[1];
    float* out = (float*)d_out;

    float* ws = (float*)d_ws;
    float*   probs    = ws;                                   // 1,048,576 floats (4 MB)
    ushort4* dbuf     = (ushort4*)(ws + 1048576);             // 16*65536*8 B (8 MB)
    float*   partials = ws + 1048576 + 2097152;               // 4096 floats
    int*     has      = (int*)(partials + 4096);              // 64 ints

    softmax_kernel<<<(NB * NPIX) / 256, 256, 0, stream>>>(pred, probs);
    init_kernel<<<1, 64, 0, stream>>>(has);
    dt_rows<<<NIMG * HH, 256, 0, stream>>>(probs, target, dbuf, has);
    dt_cols_loss<<<NIMG * WW, 256, 0, stream>>>(dbuf, probs, target, has, partials);
    final_kernel<<<1, 256, 0, stream>>>(partials, out);
}

// Round 3
// 53.748 us; speedup vs baseline: 12.6614x; 2.7631x over previous
//
#include <hip/hip_runtime.h>

#define HH 256
#define WW 256
#define NB 4
#define NC 4
#define NPIX (HH*WW)            // 65536
#define NIMG (NB*NC)            // 16
#define TOTAL (NB*NC*HH*WW)     // 1048576
#define INF_G (1<<30)

__device__ __forceinline__ float wave_reduce(float v) {
    #pragma unroll
    for (int off = 32; off > 0; off >>= 1) v += __shfl_down(v, off);
    return v;
}

// probs = softmax(pred, axis=1)
__global__ void softmax_kernel(const float* __restrict__ pred, float* __restrict__ probs) {
    int idx = blockIdx.x * 256 + threadIdx.x;   // over NB*HH*WW
    int b = idx >> 16;
    int pix = idx & (NPIX - 1);
    const float* base = pred + (size_t)b * NC * NPIX + pix;
    float v0 = base[0 * NPIX], v1 = base[1 * NPIX], v2 = base[2 * NPIX], v3 = base[3 * NPIX];
    float m = fmaxf(fmaxf(v0, v1), fmaxf(v2, v3));
    float e0 = expf(v0 - m), e1 = expf(v1 - m), e2 = expf(v2 - m), e3 = expf(v3 - m);
    float inv = 1.0f / (e0 + e1 + e2 + e3);
    float* ob = probs + (size_t)b * NC * NPIX + pix;
    ob[0 * NPIX] = e0 * inv;
    ob[1 * NPIX] = e1 * inv;
    ob[2 * NPIX] = e2 * inv;
    ob[3 * NPIX] = e3 * inv;
}

// distance from x to nearest set bit in a 256-bit mask (4 u64 words); INT_MAX if none
__device__ __forceinline__ int nearest_dist(const unsigned long long* m, int x) {
    int best = 0x7fffffff;
    #pragma unroll
    for (int w = 0; w < 4; ++w) {
        unsigned long long mm = m[w];
        if (!mm) continue;
        int rel = x - (w << 6);
        // left side: highest set bit at position <= rel
        unsigned long long lmask = (rel >= 63) ? ~0ull
                                 : ((rel < 0) ? 0ull : ((2ull << (rel & 63)) - 1ull));
        unsigned long long lm = mm & lmask;
        if (lm) best = min(best, rel - (63 - __clzll(lm)));
        // right side: lowest set bit at position >= rel
        unsigned long long rmask = (rel <= 0) ? ~0ull
                                 : ((rel > 63) ? 0ull : (~0ull << (rel & 63)));
        unsigned long long rm = mm & rmask;
        if (rm) best = min(best, (__ffsll((long long)rm) - 1) - rel);
    }
    return best;
}

// Row pass: per (img, y): build 256-bit site masks for 4 variants, nearest-bit distance.
// dbuf layout: ushort4 per (img,y,x): {d_v0, d_v1, d_v2, d_v3}; 0xFFFF = row empty.
// v0 = ~fgP, v1 = fgP, v2 = ~fgT, v3 = fgT
__global__ void dt_rows(const float* __restrict__ probs, const int* __restrict__ target,
                        ushort4* __restrict__ dbuf) {
    int blk = blockIdx.x;
    int img = blk >> 8, y = blk & 255;
    int b = img >> 2, c = img & 3;
    int x = threadIdx.x;

    float p = probs[((size_t)img * HH + y) * WW + x];
    int tc  = target[((size_t)b * HH + y) * WW + x];
    bool fgP = p > 0.5f;
    bool fgT = (tc == c);

    __shared__ unsigned long long mP[4], mT[4];
    unsigned long long bp = __ballot(fgP);
    unsigned long long bt = __ballot(fgT);
    int wave = x >> 6;
    if ((x & 63) == 0) { mP[wave] = bp; mT[wave] = bt; }
    __syncthreads();

    unsigned long long wp[4], wt[4], np[4], nt[4];
    #pragma unroll
    for (int w = 0; w < 4; ++w) {
        wp[w] = mP[w]; wt[w] = mT[w];
        np[w] = ~wp[w]; nt[w] = ~wt[w];
    }

    int d0 = nearest_dist(np, x);   // ~fgP
    int d1 = nearest_dist(wp, x);   // fgP
    int d2 = nearest_dist(nt, x);   // ~fgT
    int d3 = nearest_dist(wt, x);   // fgT

    ushort4 out;
    out.x = (d0 > 255) ? 0xFFFF : (unsigned short)d0;
    out.y = (d1 > 255) ? 0xFFFF : (unsigned short)d1;
    out.z = (d2 > 255) ? 0xFFFF : (unsigned short)d2;
    out.w = (d3 > 255) ? 0xFFFF : (unsigned short)d3;
    dbuf[((size_t)img * HH + y) * WW + x] = out;
}

// Column pass + loss, fused. block = (img, x), thread = y.
// best(y) = min_j d_row(j)^2 + (y-j)^2, searched outward with early exit.
// any(fgP) over the image == exists row with dv.y != 0xFFFF (row-DT marks whole-row-empty),
// so the gating flags are computed locally — no global atomics needed.
__global__ void dt_cols_loss(const ushort4* __restrict__ dbuf, const float* __restrict__ probs,
                             const int* __restrict__ target,
                             float* __restrict__ partials) {
    int blk = blockIdx.x;
    int img = blk >> 8, x = blk & 255;
    int b = img >> 2, c = img & 3;
    int y = threadIdx.x;

    __shared__ int g[4][HH];
    __shared__ int sP[4], sT[4];
    ushort4 dv = dbuf[((size_t)img * HH + y) * WW + x];
    g[0][y] = (dv.x == 0xFFFF) ? INF_G : (int)dv.x * (int)dv.x;
    g[1][y] = (dv.y == 0xFFFF) ? INF_G : (int)dv.y * (int)dv.y;
    g[2][y] = (dv.z == 0xFFFF) ? INF_G : (int)dv.z * (int)dv.z;
    g[3][y] = (dv.w == 0xFFFF) ? INF_G : (int)dv.w * (int)dv.w;
    // per-image "any fg" flags, derived locally
    unsigned long long bP = __ballot(dv.y != 0xFFFF);
    unsigned long long bT = __ballot(dv.w != 0xFFFF);
    int lane = y & 63, wv = y >> 6;
    if (lane == 0) { sP[wv] = (bP != 0ull); sT[wv] = (bT != 0ull); }
    __syncthreads();

    int hs1 = sP[0] | sP[1] | sP[2] | sP[3];   // any(fgP)
    int hs3 = sT[0] | sT[1] | sT[2] | sT[3];   // any(fgT)

    float dt[4];
    #pragma unroll
    for (int v = 0; v < 4; ++v) {
        int best = g[v][y];
        for (int s = 1; s < HH; ++s) {
            int ss = s * s;
            if (ss >= best) break;
            int jm = y - s;
            if (jm >= 0) best = min(best, g[v][jm] + ss);
            int jp = y + s;
            if (jp < HH) best = min(best, g[v][jp] + ss);
        }
        dt[v] = (best >= INF_G) ? sqrtf(1.0e9f) : sqrtf((float)best);
    }

    float p = probs[((size_t)img * HH + y) * WW + x];
    float t = (target[((size_t)b * HH + y) * WW + x] == c) ? 1.0f : 0.0f;
    float pe = (p - t) * (p - t);
    float pd = hs1 ? (dt[0] + dt[1]) : 0.0f;
    float td = hs3 ? (dt[2] + dt[3]) : 0.0f;
    float val = pe * (pd * pd + td * td);

    val = wave_reduce(val);
    __shared__ float sred[4];
    if (lane == 0) sred[wv] = val;
    __syncthreads();
    if (threadIdx.x == 0)
        partials[blk] = sred[0] + sred[1] + sred[2] + sred[3];
}

__global__ void final_kernel(const float* __restrict__ partials, float* __restrict__ out) {
    float a = 0.0f;
    for (int i = threadIdx.x; i < 4096; i += 256) a += partials[i];
    a = wave_reduce(a);
    __shared__ float s[4];
    int lane = threadIdx.x & 63, wave = threadIdx.x >> 6;
    if (lane == 0) s[wave] = a;
    __syncthreads();
    if (threadIdx.x == 0)
        out[0] = (s[0] + s[1] + s[2] + s[3]) * (1.0f / (float)TOTAL);
}

extern "C" void kernel_launch(void* const* d_in, const int* in_sizes, int n_in,
                              void* d_out, int out_size, void* d_ws, size_t ws_size,
                              hipStream_t stream) {
    const float* pred  = (const float*)d_in[0];
    const int* target  = (const int*)d_in[1];
    float* out = (float*)d_out;

    float* ws = (float*)d_ws;
    float*   probs    = ws;                                   // 1,048,576 floats (4 MB)
    ushort4* dbuf     = (ushort4*)(ws + 1048576);             // 16*65536*8 B (8 MB)
    float*   partials = ws + 1048576 + 2097152;               // 4096 floats

    softmax_kernel<<<(NB * NPIX) / 256, 256, 0, stream>>>(pred, probs);
    dt_rows<<<NIMG * HH, 256, 0, stream>>>(probs, target, dbuf);
    dt_cols_loss<<<NIMG * WW, 256, 0, stream>>>(dbuf, probs, target, partials);
    final_kernel<<<1, 256, 0, stream>>>(partials, out);
}

// Round 4
// 42.520 us; speedup vs baseline: 16.0048x; 1.2641x over previous
//
#include <hip/hip_runtime.h>

#define HH 256
#define WW 256
#define NB 4
#define NC 4
#define NPIX (HH*WW)            // 65536
#define NIMG (NB*NC)            // 16
#define TOTAL (NB*NC*HH*WW)     // 1048576
#define INF_G (1<<30)

__device__ __forceinline__ float wave_reduce(float v) {
    #pragma unroll
    for (int off = 32; off > 0; off >>= 1) v += __shfl_down(v, off);
    return v;
}

// distance from x to nearest set bit in a 256-bit mask (4 u64 words); INT_MAX if none
__device__ __forceinline__ int nearest_dist(const unsigned long long* m, int x) {
    int best = 0x7fffffff;
    #pragma unroll
    for (int w = 0; w < 4; ++w) {
        unsigned long long mm = m[w];
        if (!mm) continue;
        int rel = x - (w << 6);
        // left side: highest set bit at position <= rel
        unsigned long long lmask = (rel >= 63) ? ~0ull
                                 : ((rel < 0) ? 0ull : ((2ull << (rel & 63)) - 1ull));
        unsigned long long lm = mm & lmask;
        if (lm) best = min(best, rel - (63 - __clzll(lm)));
        // right side: lowest set bit at position >= rel
        unsigned long long rmask = (rel <= 0) ? ~0ull
                                 : ((rel > 63) ? 0ull : (~0ull << (rel & 63)));
        unsigned long long rm = mm & rmask;
        if (rm) best = min(best, (__ffsll((long long)rm) - 1) - rel);
    }
    return best;
}

// Fused softmax + row-DT. block = (b, y); thread = x.
// Reads pred rows for all 4 classes, softmax in-register, builds 8 ballot masks,
// does all 16 nearest-bit searches. Writes TRANSPOSED outputs so the column pass
// reads coalesced:
//   dbuf_t[img][x][y] = ushort4{d(~fgP), d(fgP), d(~fgT), d(fgT)}  (0xFFFF = row empty)
//   peT  [img][x][y] = (p - t)^2
__global__ void fused_rows(const float* __restrict__ pred, const int* __restrict__ target,
                           ushort4* __restrict__ dbuf_t, float* __restrict__ peT) {
    int blk = blockIdx.x;           // b*256 + y
    int b = blk >> 8, y = blk & 255;
    int x = threadIdx.x;

    const float* base = pred + (((size_t)b * NC) * HH + y) * WW + x;
    float v0 = base[0 * (size_t)NPIX];
    float v1 = base[1 * (size_t)NPIX];
    float v2 = base[2 * (size_t)NPIX];
    float v3 = base[3 * (size_t)NPIX];
    float m = fmaxf(fmaxf(v0, v1), fmaxf(v2, v3));
    float e0 = expf(v0 - m), e1 = expf(v1 - m), e2 = expf(v2 - m), e3 = expf(v3 - m);
    float inv = 1.0f / (e0 + e1 + e2 + e3);
    float p[4] = { e0 * inv, e1 * inv, e2 * inv, e3 * inv };

    int tc = target[((size_t)b * HH + y) * WW + x];

    __shared__ unsigned long long mP[4][4], mT[4][4];   // [class][word]
    int lane = x & 63, wave = x >> 6;
    #pragma unroll
    for (int c = 0; c < 4; ++c) {
        unsigned long long bp = __ballot(p[c] > 0.5f);
        unsigned long long bt = __ballot(tc == c);
        if (lane == 0) { mP[c][wave] = bp; mT[c][wave] = bt; }
    }
    __syncthreads();

    #pragma unroll
    for (int c = 0; c < 4; ++c) {
        unsigned long long wp[4], wt[4], np[4], nt[4];
        #pragma unroll
        for (int w = 0; w < 4; ++w) {
            wp[w] = mP[c][w]; wt[w] = mT[c][w];
            np[w] = ~wp[w];   nt[w] = ~wt[w];
        }
        int d0 = nearest_dist(np, x);   // ~fgP  (fg_dist sites)
        int d1 = nearest_dist(wp, x);   // fgP   (bg_dist sites)
        int d2 = nearest_dist(nt, x);   // ~fgT
        int d3 = nearest_dist(wt, x);   // fgT

        ushort4 out;
        out.x = (d0 > 255) ? 0xFFFF : (unsigned short)d0;
        out.y = (d1 > 255) ? 0xFFFF : (unsigned short)d1;
        out.z = (d2 > 255) ? 0xFFFF : (unsigned short)d2;
        out.w = (d3 > 255) ? 0xFFFF : (unsigned short)d3;

        size_t ti = (((size_t)(b * NC + c)) * WW + x) * HH + y;   // transposed
        dbuf_t[ti] = out;

        float t = (tc == c) ? 1.0f : 0.0f;
        float d = p[c] - t;
        peT[ti] = d * d;
    }
}

// Column pass + loss, fused. block = (img, x), thread = y. All loads coalesced.
// best(y) = min_j d_row(j)^2 + (y-j)^2, searched outward with early exit.
// any(fg) over the image == exists row with d != 0xFFFF (row-DT marks whole-row-empty).
__global__ void dt_cols_loss(const ushort4* __restrict__ dbuf_t, const float* __restrict__ peT,
                             float* __restrict__ partials) {
    int blk = blockIdx.x;
    int img = blk >> 8, x = blk & 255;
    int y = threadIdx.x;

    size_t ti = (((size_t)img) * WW + x) * HH + y;

    __shared__ int g[4][HH];
    __shared__ int sP[4], sT[4];
    ushort4 dv = dbuf_t[ti];
    g[0][y] = (dv.x == 0xFFFF) ? INF_G : (int)dv.x * (int)dv.x;
    g[1][y] = (dv.y == 0xFFFF) ? INF_G : (int)dv.y * (int)dv.y;
    g[2][y] = (dv.z == 0xFFFF) ? INF_G : (int)dv.z * (int)dv.z;
    g[3][y] = (dv.w == 0xFFFF) ? INF_G : (int)dv.w * (int)dv.w;
    // per-image "any fg" flags, derived locally
    unsigned long long bP = __ballot(dv.y != 0xFFFF);
    unsigned long long bT = __ballot(dv.w != 0xFFFF);
    int lane = y & 63, wv = y >> 6;
    if (lane == 0) { sP[wv] = (bP != 0ull); sT[wv] = (bT != 0ull); }
    __syncthreads();

    int hs1 = sP[0] | sP[1] | sP[2] | sP[3];   // any(fgP)
    int hs3 = sT[0] | sT[1] | sT[2] | sT[3];   // any(fgT)

    float dt[4];
    #pragma unroll
    for (int v = 0; v < 4; ++v) {
        int best = g[v][y];
        for (int s = 1; s < HH; ++s) {
            int ss = s * s;
            if (ss >= best) break;
            int jm = y - s;
            if (jm >= 0) best = min(best, g[v][jm] + ss);
            int jp = y + s;
            if (jp < HH) best = min(best, g[v][jp] + ss);
        }
        dt[v] = (best >= INF_G) ? sqrtf(1.0e9f) : sqrtf((float)best);
    }

    float pe = peT[ti];
    float pd = hs1 ? (dt[0] + dt[1]) : 0.0f;
    float td = hs3 ? (dt[2] + dt[3]) : 0.0f;
    float val = pe * (pd * pd + td * td);

    val = wave_reduce(val);
    __shared__ float sred[4];
    if (lane == 0) sred[wv] = val;
    __syncthreads();
    if (threadIdx.x == 0)
        partials[blk] = sred[0] + sred[1] + sred[2] + sred[3];
}

__global__ void final_kernel(const float* __restrict__ partials, float* __restrict__ out) {
    float a = 0.0f;
    for (int i = threadIdx.x; i < 4096; i += 256) a += partials[i];
    a = wave_reduce(a);
    __shared__ float s[4];
    int lane = threadIdx.x & 63, wave = threadIdx.x >> 6;
    if (lane == 0) s[wave] = a;
    __syncthreads();
    if (threadIdx.x == 0)
        out[0] = (s[0] + s[1] + s[2] + s[3]) * (1.0f / (float)TOTAL);
}

extern "C" void kernel_launch(void* const* d_in, const int* in_sizes, int n_in,
                              void* d_out, int out_size, void* d_ws, size_t ws_size,
                              hipStream_t stream) {
    const float* pred  = (const float*)d_in[0];
    const int* target  = (const int*)d_in[1];
    float* out = (float*)d_out;

    float* ws = (float*)d_ws;
    ushort4* dbuf_t   = (ushort4*)ws;                         // 16*65536*8 B (8 MB)
    float*   peT      = ws + 2097152;                         // 1,048,576 floats (4 MB)
    float*   partials = ws + 2097152 + 1048576;               // 4096 floats

    fused_rows<<<NB * HH, 256, 0, stream>>>(pred, target, dbuf_t, peT);
    dt_cols_loss<<<NIMG * WW, 256, 0, stream>>>(dbuf_t, peT, partials);
    final_kernel<<<1, 256, 0, stream>>>(partials, out);
}